// Round 13
// baseline (4910.310 us; speedup 1.0000x reference)
//
#include <hip/hip_runtime.h>
#include <math.h>

#define T_LEN 1000
#define BATCH 16
#define MEL   80
#define HID   512
#define NCLS  64
#define SL    8        // blocks per chain (8 x 512 threads) — register-feasible geometry

__device__ __forceinline__ float fast_tanh(float x) {
    float e = __expf(2.0f * x);
    return 1.0f - 2.0f / (e + 1.0f);
}
__device__ __forceinline__ float fast_sigmoid(float x) {
    return 1.0f / (1.0f + __expf(-x));
}

// packed (value, epoch) 8B atom. Published via __hip_atomic_store AGENT,
// polled via the r6-proven one-wait asm gather. Exchange ledger closed:
// ~3.3us/step is the rendezvous floor (r3/r4/r5/r6/r8 all failed to move it).
// Slack-work placement rules learned r10/r12:
//   (1) NOTHING between the end-of-step barrier and the publish (r10:
//       a NT store there delayed publish visibility ~3.8k cyc).
//   (2) NT stores must be issued AFTER the last __syncthreads() of the
//       step (r12: __syncthreads compiles to vmcnt(0)+s_barrier, so a
//       barrier after an NT store drains it to HBM on the critical path).
//       The only safe waiter is the poll's own vmcnt(0), which overlaps
//       the rendezvous wait (r9 proved this position free).
__device__ __forceinline__ unsigned long long pack_pair(float v, unsigned e) {
    return ((unsigned long long)e << 32) | (unsigned long long)__float_as_uint(v);
}
__device__ __forceinline__ float pair_val(unsigned long long p) {
    return __uint_as_float((unsigned)(p & 0xffffffffull));
}
__device__ __forceinline__ unsigned pair_epoch(unsigned long long p) {
    return (unsigned)(p >> 32);
}

// one-shot LLC bulk load of 64 CONTIGUOUS floats (asm-defined => cannot be
// rematerialized => register-resident). NOT used in any spin loop.
__device__ __forceinline__ void llc_load16c(const float* base, float4 (&r)[16]) {
    asm volatile(
        "global_load_dwordx4 %0, %16, off sc0 sc1\n\t"
        "global_load_dwordx4 %1, %16, off offset:16 sc0 sc1\n\t"
        "global_load_dwordx4 %2, %16, off offset:32 sc0 sc1\n\t"
        "global_load_dwordx4 %3, %16, off offset:48 sc0 sc1\n\t"
        "global_load_dwordx4 %4, %16, off offset:64 sc0 sc1\n\t"
        "global_load_dwordx4 %5, %16, off offset:80 sc0 sc1\n\t"
        "global_load_dwordx4 %6, %16, off offset:96 sc0 sc1\n\t"
        "global_load_dwordx4 %7, %16, off offset:112 sc0 sc1\n\t"
        "global_load_dwordx4 %8, %16, off offset:128 sc0 sc1\n\t"
        "global_load_dwordx4 %9, %16, off offset:144 sc0 sc1\n\t"
        "global_load_dwordx4 %10, %16, off offset:160 sc0 sc1\n\t"
        "global_load_dwordx4 %11, %16, off offset:176 sc0 sc1\n\t"
        "global_load_dwordx4 %12, %16, off offset:192 sc0 sc1\n\t"
        "global_load_dwordx4 %13, %16, off offset:208 sc0 sc1\n\t"
        "global_load_dwordx4 %14, %16, off offset:224 sc0 sc1\n\t"
        "global_load_dwordx4 %15, %16, off offset:240 sc0 sc1\n\t"
        "s_waitcnt vmcnt(0)"
        : "=&v"(r[0]), "=&v"(r[1]), "=&v"(r[2]), "=&v"(r[3]),
          "=&v"(r[4]), "=&v"(r[5]), "=&v"(r[6]), "=&v"(r[7]),
          "=&v"(r[8]), "=&v"(r[9]), "=&v"(r[10]), "=&v"(r[11]),
          "=&v"(r[12]), "=&v"(r[13]), "=&v"(r[14]), "=&v"(r[15])
        : "v"(base)
        : "memory");
}

// 8 contiguous floats (32B) to registers, same coherence class.
__device__ __forceinline__ void llc_load2c(const float* base, float4 (&r)[2]) {
    asm volatile(
        "global_load_dwordx4 %0, %2, off sc0 sc1\n\t"
        "global_load_dwordx4 %1, %2, off offset:16 sc0 sc1\n\t"
        "s_waitcnt vmcnt(0)"
        : "=&v"(r[0]), "=&v"(r[1])
        : "v"(base)
        : "memory");
}

// K0: init pair buffer to epoch 0 (never matches poll targets >= 1).
#define PART_WORDS (BATCH * 2 * SL * HID)
__global__ void k0_init(unsigned long long* part) {
    int i = blockIdx.x * 256 + threadIdx.x;
    if (i < PART_WORDS) part[i] = 0ull;
}

// K1: per t: x_norm0 from feats, be0 = x_norm0 @ B0^T
__global__ __launch_bounds__(256) void k1_be0(const float* __restrict__ feats,
                                              const float* __restrict__ B0,
                                              float* __restrict__ be0) {
    const int t = blockIdx.x;
    const int tid = threadIdx.x;
    __shared__ float xf[BATCH][MEL];
    __shared__ float sc[BATCH];
    for (int idx = tid; idx < BATCH * MEL; idx += 256) {
        int b = idx / MEL, m = idx % MEL;
        xf[b][m] = feats[b * (T_LEN * MEL) + t * MEL + m];
    }
    __syncthreads();
    if (tid < BATCH) {
        float ss = 0.f;
        for (int m = 0; m < MEL; ++m) { float v = xf[tid][m]; ss += v * v; }
        sc[tid] = fmaxf(sqrtf(ss), 1e-6f);
    }
    __syncthreads();
    for (int idx = tid; idx < BATCH * MEL; idx += 256) {
        int b = idx / MEL, m = idx % MEL;
        float v = xf[b][m] / sc[b];
        xf[b][m] = fminf(fmaxf(v, -1.f), 1.f);
    }
    __syncthreads();
    for (int j = tid; j < HID; j += 256) {
        float acc[BATCH];
        #pragma unroll
        for (int b = 0; b < BATCH; ++b) acc[b] = 0.f;
        const float* brow = B0 + j * MEL;
        for (int k = 0; k < MEL; k += 4) {
            float4 w = *(const float4*)(brow + k);
            #pragma unroll
            for (int b = 0; b < BATCH; ++b) {
                float4 xv = *(const float4*)(&xf[b][k]);
                acc[b] += w.x * xv.x + w.y * xv.y + w.z * xv.z + w.w * xv.w;
            }
        }
        #pragma unroll
        for (int b = 0; b < BATCH; ++b)
            be0[(t * BATCH + b) * HID + j] = acc[b];
    }
}

// K3: sequential recurrence, ONE exchange per step (r6-proven exchange),
// be1/xs fused post-publish (r9), head partial for t-1 fused LAST in the
// slack — after slack B's barriers, immediately before the poll (the store
// position r9 proved free; r12 had it before the barriers and each
// __syncthreads drained the NT store to HBM on the critical path).
__global__ __launch_bounds__(512, 1) void k3_fused(
    const float* __restrict__ be0g,
    const float* __restrict__ C1, const float* __restrict__ W1,
    const float* __restrict__ B1,
    const float* __restrict__ a1, const float* __restrict__ tau,
    const float* __restrict__ gam,
    const float* __restrict__ head_w,
    float* __restrict__ pout,
    unsigned long long* part)
{
    const int chain = blockIdx.x & 15;
    const int slice = blockIdx.x >> 4;        // 0..7
    const int tid = threadIdx.x;              // 0..511 ; phase-1 row = tid
    const int w = tid >> 6;                   // wave 0..7
    const int lane = tid & 63;
    const int jq = tid >> 3;                  // phase-2 column within slice 0..63
    const int kc = tid & 7;                   // phase-2 k-chunk 0..7
    const int j2 = slice * 64 + jq;           // phase-2 global output column
    const bool lead = (kc == 0);
    const int hc = tid >> 3;                  // head class 0..63
    const int hq = tid & 7;                   // head input-group 0..7

    // 48 float4 weights + 4 float4 head slice, asm-defined => resident
    float4 wC[16], wW[16], wB[16], hwh[2], hwb[2];
    llc_load16c(C1 + (size_t)tid * HID + slice * 64, wC);
    llc_load16c(W1 + (size_t)j2 * HID + kc * 64, wW);
    llc_load16c(B1 + (size_t)j2 * HID + kc * 64, wB);
    llc_load2c(head_w + (size_t)hc * (2 * HID) + slice * 64 + hq * 8, hwh);
    llc_load2c(head_w + (size_t)hc * (2 * HID) + HID + slice * 64 + hq * 8, hwb);

    const float tauv = tau[0], gamv = gam[0];
    const float siga = fast_sigmoid(a1[j2]);

    unsigned long long* pc = part + (size_t)chain * (2 * SL * HID);

    __shared__ float h_s[64];                      // own h slice (broadcast reads)
    __shared__ float b1_s[64];                     // own be1 slice (for head)
    __shared__ __align__(16) float e_s[HID + 32];  // err, padded per 64-chunk
    __shared__ __align__(16) float x_s[HID + 32];  // normalized be0 row, padded
    __shared__ float sq_s[8];
    __shared__ float xsq_s[8];

    float hj = 0.f;                           // lead lanes: h for column j2
    if (tid < 64) h_s[tid] = 0.f;

    // ---- prologue: t=0 streams; compute cur_xs, cur_be1 locally ----
    float cur_be0 = be0g[(size_t)chain * HID + tid];
    float cur_xs, cur_be1 = 0.f;
    {
        float sq = cur_be0 * cur_be0;
        #pragma unroll
        for (int off = 32; off > 0; off >>= 1) sq += __shfl_down(sq, off, 64);
        if (lane == 0) xsq_s[w] = sq;
        __syncthreads();
        float ssX = ((xsq_s[0] + xsq_s[1]) + (xsq_s[2] + xsq_s[3]))
                  + ((xsq_s[4] + xsq_s[5]) + (xsq_s[6] + xsq_s[7]));
        cur_xs = fmaxf(sqrtf(ssX), 1e-6f);
        float xn = cur_be0 / cur_xs;
        x_s[tid + (tid >> 6) * 4] = fminf(fmaxf(xn, -1.f), 1.f);
        __syncthreads();
        const float* xb = x_s + kc * 68;
        float q0 = 0.f, q1 = 0.f, q2 = 0.f, q3 = 0.f;
        #pragma unroll
        for (int i = 0; i < 16; ++i) {
            float4 v4 = *(const float4*)(xb + 4 * i);
            q0 += wB[i].x * v4.x; q1 += wB[i].y * v4.y;
            q2 += wB[i].z * v4.z; q3 += wB[i].w * v4.w;
        }
        float bq = (q0 + q1) + (q2 + q3);
        bq += __shfl_down(bq, 4, 8);
        bq += __shfl_down(bq, 2, 8);
        bq += __shfl_down(bq, 1, 8);
        if (lead) cur_be1 = bq;
        __syncthreads();   // x_s free; h_s visible
    }

    for (int t = 0; t < T_LEN; ++t) {
        // issue next-row stream early (consumed in the slack window)
        float nxt_be0 = 0.f;
        if (t + 1 < T_LEN)
            nxt_be0 = be0g[(size_t)((t + 1) * BATCH + chain) * HID + tid];
        const unsigned tag = (unsigned)(t + 1);
        unsigned long long* ps = pc + (size_t)(t & 1) * (SL * HID);

        // ---- phase 1: 64-MAC partial of dp[tid] over own h slice ----
        // (NOTHING between the previous barrier and this publish)
        {
            float p0 = 0.f, p1 = 0.f, p2 = 0.f, p3 = 0.f;
            #pragma unroll
            for (int i = 0; i < 16; ++i) {
                float4 hv = *(const float4*)(h_s + 4 * i);   // broadcast, no conflict
                p0 += wC[i].x * hv.x; p1 += wC[i].y * hv.y;
                p2 += wC[i].z * hv.z; p3 += wC[i].w * hv.w;
            }
            float pp = (p0 + p1) + (p2 + p3);
            __hip_atomic_store(&ps[slice * HID + tid], pack_pair(pp, tag),
                               __ATOMIC_RELAXED, __HIP_MEMORY_SCOPE_AGENT);
        }

        // ---- slack B: be1(t+1) + xs(t+1), local (barriers BEFORE any NT store) ----
        float nxt_xs = 0.f, nxt_be1 = 0.f;
        if (t + 1 < T_LEN) {
            float sq = nxt_be0 * nxt_be0;
            #pragma unroll
            for (int off = 32; off > 0; off >>= 1) sq += __shfl_down(sq, off, 64);
            if (lane == 0) xsq_s[w] = sq;
            __syncthreads();
            float ssX = ((xsq_s[0] + xsq_s[1]) + (xsq_s[2] + xsq_s[3]))
                      + ((xsq_s[4] + xsq_s[5]) + (xsq_s[6] + xsq_s[7]));
            nxt_xs = fmaxf(sqrtf(ssX), 1e-6f);
            float xn = nxt_be0 / nxt_xs;
            x_s[tid + (tid >> 6) * 4] = fminf(fmaxf(xn, -1.f), 1.f);
            __syncthreads();
            const float* xb = x_s + kc * 68;
            float q0 = 0.f, q1 = 0.f, q2 = 0.f, q3 = 0.f;
            #pragma unroll
            for (int i = 0; i < 16; ++i) {
                float4 v4 = *(const float4*)(xb + 4 * i);
                q0 += wB[i].x * v4.x; q1 += wB[i].y * v4.y;
                q2 += wB[i].z * v4.z; q3 += wB[i].w * v4.w;
            }
            float bq = (q0 + q1) + (q2 + q3);
            bq += __shfl_down(bq, 4, 8);
            bq += __shfl_down(bq, 2, 8);
            bq += __shfl_down(bq, 1, 8);
            if (lead) nxt_be1 = bq;
        }

        // ---- slack A (LAST, no barrier after): head partial for t-1 ----
        // h_s/b1_s still hold step t-1's values (phase-2 hasn't run yet).
        // The pout NT store's only waiter is the poll's vmcnt(0), which
        // overlaps the rendezvous wait (r9-proven-free position).
        if (t >= 1) {
            const float* hb = h_s + hq * 8;
            const float* bb = b1_s + hq * 8;
            float4 h0 = *(const float4*)(hb);
            float4 h1 = *(const float4*)(hb + 4);
            float4 b0 = *(const float4*)(bb);
            float4 b1 = *(const float4*)(bb + 4);
            float p = hwh[0].x * h0.x + hwh[0].y * h0.y + hwh[0].z * h0.z + hwh[0].w * h0.w
                    + hwh[1].x * h1.x + hwh[1].y * h1.y + hwh[1].z * h1.z + hwh[1].w * h1.w
                    + hwb[0].x * b0.x + hwb[0].y * b0.y + hwb[0].z * b0.z + hwb[0].w * b0.w
                    + hwb[1].x * b1.x + hwb[1].y * b1.y + hwb[1].z * b1.z + hwb[1].w * b1.w;
            p += __shfl_down(p, 4, 8);
            p += __shfl_down(p, 2, 8);
            p += __shfl_down(p, 1, 8);
            if (hq == 0)
                __builtin_nontemporal_store(p,
                    &pout[((size_t)((t - 1) * BATCH + chain) * SL + slice) * NCLS + hc]);
        }

        // ---- poll: 8 single-producer pairs, ONE asm round-trip per round ----
        float dp;
        {
            const unsigned long long* a0 = ps + 0 * HID + tid;
            const unsigned long long* a1p = ps + 1 * HID + tid;
            const unsigned long long* a2 = ps + 2 * HID + tid;
            const unsigned long long* a3 = ps + 3 * HID + tid;
            const unsigned long long* a4 = ps + 4 * HID + tid;
            const unsigned long long* a5 = ps + 5 * HID + tid;
            const unsigned long long* a6 = ps + 6 * HID + tid;
            const unsigned long long* a7 = ps + 7 * HID + tid;
            unsigned long long q0, q1, q2, q3, q4, q5, q6, q7;
            int rounds = 0;
            for (;;) {
                asm volatile(
                    "global_load_dwordx2 %0, %8, off sc0 sc1\n\t"
                    "global_load_dwordx2 %1, %9, off sc0 sc1\n\t"
                    "global_load_dwordx2 %2, %10, off sc0 sc1\n\t"
                    "global_load_dwordx2 %3, %11, off sc0 sc1\n\t"
                    "global_load_dwordx2 %4, %12, off sc0 sc1\n\t"
                    "global_load_dwordx2 %5, %13, off sc0 sc1\n\t"
                    "global_load_dwordx2 %6, %14, off sc0 sc1\n\t"
                    "global_load_dwordx2 %7, %15, off sc0 sc1\n\t"
                    "s_waitcnt vmcnt(0)"
                    : "=&v"(q0), "=&v"(q1), "=&v"(q2), "=&v"(q3),
                      "=&v"(q4), "=&v"(q5), "=&v"(q6), "=&v"(q7)
                    : "v"(a0), "v"(a1p), "v"(a2), "v"(a3),
                      "v"(a4), "v"(a5), "v"(a6), "v"(a7)
                    : "memory");
                bool ok = (pair_epoch(q0) == tag) & (pair_epoch(q1) == tag)
                        & (pair_epoch(q2) == tag) & (pair_epoch(q3) == tag)
                        & (pair_epoch(q4) == tag) & (pair_epoch(q5) == tag)
                        & (pair_epoch(q6) == tag) & (pair_epoch(q7) == tag);
                if (__all(ok)) break;
                // guaranteed-progress fallback: proven atomic gather
                if (++rounds > 200000) {
                    q0 = __hip_atomic_load(a0, __ATOMIC_RELAXED, __HIP_MEMORY_SCOPE_AGENT);
                    q1 = __hip_atomic_load(a1p, __ATOMIC_RELAXED, __HIP_MEMORY_SCOPE_AGENT);
                    q2 = __hip_atomic_load(a2, __ATOMIC_RELAXED, __HIP_MEMORY_SCOPE_AGENT);
                    q3 = __hip_atomic_load(a3, __ATOMIC_RELAXED, __HIP_MEMORY_SCOPE_AGENT);
                    q4 = __hip_atomic_load(a4, __ATOMIC_RELAXED, __HIP_MEMORY_SCOPE_AGENT);
                    q5 = __hip_atomic_load(a5, __ATOMIC_RELAXED, __HIP_MEMORY_SCOPE_AGENT);
                    q6 = __hip_atomic_load(a6, __ATOMIC_RELAXED, __HIP_MEMORY_SCOPE_AGENT);
                    q7 = __hip_atomic_load(a7, __ATOMIC_RELAXED, __HIP_MEMORY_SCOPE_AGENT);
                    bool ok2 = (pair_epoch(q0) == tag) & (pair_epoch(q1) == tag)
                             & (pair_epoch(q2) == tag) & (pair_epoch(q3) == tag)
                             & (pair_epoch(q4) == tag) & (pair_epoch(q5) == tag)
                             & (pair_epoch(q6) == tag) & (pair_epoch(q7) == tag);
                    if (__all(ok2)) break;
                    rounds = 0;
                }
                __builtin_amdgcn_s_sleep(1);
            }
            dp = ((pair_val(q0) + pair_val(q1)) + (pair_val(q2) + pair_val(q3)))
               + ((pair_val(q4) + pair_val(q5)) + (pair_val(q6) + pair_val(q7)));
        }

        // ---- err vector; stage padded for conflict-free phase 2 ----
        {
            float err = cur_be0 - fast_tanh(dp) * cur_xs;
            e_s[tid + (tid >> 6) * 4] = err;
            float sq = err * err;
            #pragma unroll
            for (int off = 32; off > 0; off >>= 1) sq += __shfl_down(sq, off, 64);
            if (lane == 0) sq_s[w] = sq;
        }
        __syncthreads();   // e_s + sq_s complete (also orders head reads
                           // of h_s/b1_s before phase-2's writes below)

        // ---- phase 2: ee = (err @ W1^T)[j2] over k-chunk, gated update ----
        {
            float ssT = ((sq_s[0] + sq_s[1]) + (sq_s[2] + sq_s[3]))
                      + ((sq_s[4] + sq_s[5]) + (sq_s[6] + sq_s[7]));
            const float* esb = e_s + kc * 68;
            float q0 = 0.f, q1 = 0.f, q2 = 0.f, q3 = 0.f;
            #pragma unroll
            for (int i = 0; i < 16; ++i) {
                float4 ev = *(const float4*)(esb + 4 * i);   // 8 groups x 16B = 32 banks
                q0 += wW[i].x * ev.x; q1 += wW[i].y * ev.y;
                q2 += wW[i].z * ev.z; q3 += wW[i].w * ev.w;
            }
            float ee = (q0 + q1) + (q2 + q3);
            ee += __shfl_down(ee, 4, 8);
            ee += __shfl_down(ee, 2, 8);
            ee += __shfl_down(ee, 1, 8);
            if (lead) {
                float rel = fminf(sqrtf(ssT) / cur_xs, 4.0f);
                float s = fast_sigmoid((rel - tauv) / gamv);
                float input_h = hj * 0.2f + cur_be1 * 0.6f + ee * s * 0.2f;
                float g = s * siga;
                hj = hj * (1.f - g) + fast_tanh(input_h) * g;
                h_s[jq] = hj;          // h1(t) slice
                b1_s[jq] = cur_be1;    // be1(t) slice
            }
        }
        __syncthreads();   // h_s/b1_s ready; e_s/x_s reads done

        cur_be0 = nxt_be0; cur_be1 = nxt_be1; cur_xs = nxt_xs;
    }

    // ---- epilogue: head partial for t = T_LEN-1 ----
    {
        const float* hb = h_s + hq * 8;
        const float* bb = b1_s + hq * 8;
        float4 h0 = *(const float4*)(hb);
        float4 h1 = *(const float4*)(hb + 4);
        float4 b0 = *(const float4*)(bb);
        float4 b1 = *(const float4*)(bb + 4);
        float p = hwh[0].x * h0.x + hwh[0].y * h0.y + hwh[0].z * h0.z + hwh[0].w * h0.w
                + hwh[1].x * h1.x + hwh[1].y * h1.y + hwh[1].z * h1.z + hwh[1].w * h1.w
                + hwb[0].x * b0.x + hwb[0].y * b0.y + hwb[0].z * b0.z + hwb[0].w * b0.w
                + hwb[1].x * b1.x + hwb[1].y * b1.y + hwb[1].z * b1.z + hwb[1].w * b1.w;
        p += __shfl_down(p, 4, 8);
        p += __shfl_down(p, 2, 8);
        p += __shfl_down(p, 1, 8);
        if (hq == 0)
            __builtin_nontemporal_store(p,
                &pout[((size_t)((T_LEN - 1) * BATCH + chain) * SL + slice) * NCLS + hc]);
    }
}

// K4lite: out[b,t,c] = head_b[c] + sum_s pout[t][b][s][c]
__global__ __launch_bounds__(1024) void k4_head(const float* __restrict__ pout,
                                                const float* __restrict__ head_b,
                                                float* __restrict__ out) {
    const int t = blockIdx.x;
    const int tid = threadIdx.x;
    const int c = tid & 63;
    const int b = tid >> 6;
    const float* pb = pout + (size_t)(t * BATCH + b) * SL * NCLS + c;
    float acc = head_b[c];
    #pragma unroll
    for (int s = 0; s < SL; ++s) acc += pb[s * NCLS];
    out[b * (T_LEN * NCLS) + t * NCLS + c] = acc;
}

extern "C" void kernel_launch(void* const* d_in, const int* in_sizes, int n_in,
                              void* d_out, int out_size, void* d_ws, size_t ws_size,
                              hipStream_t stream) {
    const float* feats  = (const float*)d_in[0];
    const float* B0     = (const float*)d_in[2];
    const float* C1     = (const float*)d_in[7];
    const float* B1     = (const float*)d_in[8];
    const float* W1     = (const float*)d_in[9];
    const float* a1     = (const float*)d_in[10];
    const float* tau1   = (const float*)d_in[11];
    const float* gam1   = (const float*)d_in[12];
    const float* head_w = (const float*)d_in[13];
    const float* head_b = (const float*)d_in[14];
    float* out = (float*)d_out;

    float* be0 = (float*)d_ws;                          // T*B*HID
    float* pout = be0 + (size_t)T_LEN * BATCH * HID;    // T*B*SL*NCLS
    unsigned long long* part =
        (unsigned long long*)(pout + (size_t)T_LEN * BATCH * SL * NCLS);

    hipLaunchKernelGGL(k0_init, dim3(512), dim3(256), 0, stream, part);
    hipLaunchKernelGGL(k1_be0, dim3(T_LEN), dim3(256), 0, stream, feats, B0, be0);
    hipLaunchKernelGGL(k3_fused, dim3(BATCH * SL), dim3(512), 0, stream,
                       be0, C1, W1, B1, a1, tau1, gam1, head_w, pout, part);
    hipLaunchKernelGGL(k4_head, dim3(T_LEN), dim3(1024), 0, stream,
                       pout, head_b, out);
}

// Round 14
// 3930.519 us; speedup vs baseline: 1.2493x; 1.2493x over previous
//
#include <hip/hip_runtime.h>
#include <math.h>

#define T_LEN 1000
#define BATCH 16
#define MEL   80
#define HID   512
#define NCLS  64
#define SL    8        // blocks per chain (8 x 512 threads) — register-feasible geometry

__device__ __forceinline__ float fast_tanh(float x) {
    float e = __expf(2.0f * x);
    return 1.0f - 2.0f / (e + 1.0f);
}
__device__ __forceinline__ float fast_sigmoid(float x) {
    return 1.0f / (1.0f + __expf(-x));
}

// packed (value, epoch) 8B atom. Published via __hip_atomic_store AGENT,
// polled via the r6-proven one-wait asm gather (fused data+validity in ONE
// load stage). Exchange ledger CLOSED: serialized loads (r4) n.s., one-wait
// (r6) n.s., flags (r3) / interleaved lines (r5) / tails (r8) all WORSE
// => ~3.3us/step is the rendezvous floor. Slack-fusion ledger: be1 GEMM in
// the publish->poll window = WIN (r9, this kernel); head partial in the
// window = LOSS at all three placements (r10/r12/r13) — do not re-add.
__device__ __forceinline__ unsigned long long pack_pair(float v, unsigned e) {
    return ((unsigned long long)e << 32) | (unsigned long long)__float_as_uint(v);
}
__device__ __forceinline__ float pair_val(unsigned long long p) {
    return __uint_as_float((unsigned)(p & 0xffffffffull));
}
__device__ __forceinline__ unsigned pair_epoch(unsigned long long p) {
    return (unsigned)(p >> 32);
}

// one-shot LLC bulk load of 64 CONTIGUOUS floats (asm-defined => cannot be
// rematerialized => register-resident). NOT used in any spin loop.
__device__ __forceinline__ void llc_load16c(const float* base, float4 (&r)[16]) {
    asm volatile(
        "global_load_dwordx4 %0, %16, off sc0 sc1\n\t"
        "global_load_dwordx4 %1, %16, off offset:16 sc0 sc1\n\t"
        "global_load_dwordx4 %2, %16, off offset:32 sc0 sc1\n\t"
        "global_load_dwordx4 %3, %16, off offset:48 sc0 sc1\n\t"
        "global_load_dwordx4 %4, %16, off offset:64 sc0 sc1\n\t"
        "global_load_dwordx4 %5, %16, off offset:80 sc0 sc1\n\t"
        "global_load_dwordx4 %6, %16, off offset:96 sc0 sc1\n\t"
        "global_load_dwordx4 %7, %16, off offset:112 sc0 sc1\n\t"
        "global_load_dwordx4 %8, %16, off offset:128 sc0 sc1\n\t"
        "global_load_dwordx4 %9, %16, off offset:144 sc0 sc1\n\t"
        "global_load_dwordx4 %10, %16, off offset:160 sc0 sc1\n\t"
        "global_load_dwordx4 %11, %16, off offset:176 sc0 sc1\n\t"
        "global_load_dwordx4 %12, %16, off offset:192 sc0 sc1\n\t"
        "global_load_dwordx4 %13, %16, off offset:208 sc0 sc1\n\t"
        "global_load_dwordx4 %14, %16, off offset:224 sc0 sc1\n\t"
        "global_load_dwordx4 %15, %16, off offset:240 sc0 sc1\n\t"
        "s_waitcnt vmcnt(0)"
        : "=&v"(r[0]), "=&v"(r[1]), "=&v"(r[2]), "=&v"(r[3]),
          "=&v"(r[4]), "=&v"(r[5]), "=&v"(r[6]), "=&v"(r[7]),
          "=&v"(r[8]), "=&v"(r[9]), "=&v"(r[10]), "=&v"(r[11]),
          "=&v"(r[12]), "=&v"(r[13]), "=&v"(r[14]), "=&v"(r[15])
        : "v"(base)
        : "memory");
}

// K0: init pair buffer to epoch 0 (never matches poll targets >= 1).
#define PART_WORDS (BATCH * 2 * SL * HID)
__global__ void k0_init(unsigned long long* part) {
    int i = blockIdx.x * 256 + threadIdx.x;
    if (i < PART_WORDS) part[i] = 0ull;
}

// K1: per t: x_norm0 from feats, be0 = x_norm0 @ B0^T
__global__ __launch_bounds__(256) void k1_be0(const float* __restrict__ feats,
                                              const float* __restrict__ B0,
                                              float* __restrict__ be0) {
    const int t = blockIdx.x;
    const int tid = threadIdx.x;
    __shared__ float xf[BATCH][MEL];
    __shared__ float sc[BATCH];
    for (int idx = tid; idx < BATCH * MEL; idx += 256) {
        int b = idx / MEL, m = idx % MEL;
        xf[b][m] = feats[b * (T_LEN * MEL) + t * MEL + m];
    }
    __syncthreads();
    if (tid < BATCH) {
        float ss = 0.f;
        for (int m = 0; m < MEL; ++m) { float v = xf[tid][m]; ss += v * v; }
        sc[tid] = fmaxf(sqrtf(ss), 1e-6f);
    }
    __syncthreads();
    for (int idx = tid; idx < BATCH * MEL; idx += 256) {
        int b = idx / MEL, m = idx % MEL;
        float v = xf[b][m] / sc[b];
        xf[b][m] = fminf(fmaxf(v, -1.f), 1.f);
    }
    __syncthreads();
    for (int j = tid; j < HID; j += 256) {
        float acc[BATCH];
        #pragma unroll
        for (int b = 0; b < BATCH; ++b) acc[b] = 0.f;
        const float* brow = B0 + j * MEL;
        for (int k = 0; k < MEL; k += 4) {
            float4 w = *(const float4*)(brow + k);
            #pragma unroll
            for (int b = 0; b < BATCH; ++b) {
                float4 xv = *(const float4*)(&xf[b][k]);
                acc[b] += w.x * xv.x + w.y * xv.y + w.z * xv.z + w.w * xv.w;
            }
        }
        #pragma unroll
        for (int b = 0; b < BATCH; ++b)
            be0[(t * BATCH + b) * HID + j] = acc[b];
    }
}

// K3: sequential recurrence, ONE exchange per step (r6-proven exchange) with
// be1/xs FUSED into the publish->poll slack window (k2 deleted):
//   Block s owns h slice [64s,64s+64). Phase 1 (k-split) publishes 512
//   partial-dp pairs slice-major. While those flow to the LLC, the block
//   computes be1(t+1) = clip(be0(t+1)/||be0||) @ B1^T for its 64 columns —
//   pure local work (stage row in LDS, normalize, 16 f4 MACs, width-8
//   reduce, lead stores to be1 global for k4). Then the poll+gather runs
//   (one-wait asm, epoch-verified, atomic fallback). Phase 2 j-split local.
__global__ __launch_bounds__(512, 1) void k3_fused(
    const float* __restrict__ be0g,
    const float* __restrict__ C1, const float* __restrict__ W1,
    const float* __restrict__ B1,
    const float* __restrict__ a1, const float* __restrict__ tau,
    const float* __restrict__ gam,
    float* __restrict__ be1g, float* __restrict__ h1s,
    unsigned long long* part)
{
    const int chain = blockIdx.x & 15;
    const int slice = blockIdx.x >> 4;        // 0..7
    const int tid = threadIdx.x;              // 0..511 ; phase-1 row = tid
    const int w = tid >> 6;                   // wave 0..7
    const int lane = tid & 63;
    const int jq = tid >> 3;                  // phase-2 column within slice 0..63
    const int kc = tid & 7;                   // phase-2 k-chunk 0..7
    const int j2 = slice * 64 + jq;           // phase-2 global output column
    const bool lead = (kc == 0);

    // 48 float4 = 192 regs of weights, asm-defined => register-resident
    // phase-1: C1[row=tid, 64*slice..+64)  phase-2: W1[j2, 64*kc..+64)
    // be1:     B1[j2, 64*kc..+64)
    float4 wC[16], wW[16], wB[16];
    llc_load16c(C1 + (size_t)tid * HID + slice * 64, wC);
    llc_load16c(W1 + (size_t)j2 * HID + kc * 64, wW);
    llc_load16c(B1 + (size_t)j2 * HID + kc * 64, wB);

    const float tauv = tau[0], gamv = gam[0];
    const float siga = fast_sigmoid(a1[j2]);

    unsigned long long* pc = part + (size_t)chain * (2 * SL * HID);

    __shared__ float h_s[64];                      // own h slice (broadcast reads)
    __shared__ __align__(16) float e_s[HID + 32];  // err, padded per 64-chunk
    __shared__ __align__(16) float x_s[HID + 32];  // normalized be0 row, padded
    __shared__ float sq_s[8];
    __shared__ float xsq_s[8];

    float hj = 0.f;                           // lead lanes: h for column j2
    if (tid < 64) h_s[tid] = 0.f;

    // ---- prologue: t=0 streams; compute cur_xs, cur_be1 locally ----
    float cur_be0 = be0g[(size_t)chain * HID + tid];
    float cur_xs, cur_be1 = 0.f;
    {
        float sq = cur_be0 * cur_be0;
        #pragma unroll
        for (int off = 32; off > 0; off >>= 1) sq += __shfl_down(sq, off, 64);
        if (lane == 0) xsq_s[w] = sq;
        __syncthreads();
        float ssX = ((xsq_s[0] + xsq_s[1]) + (xsq_s[2] + xsq_s[3]))
                  + ((xsq_s[4] + xsq_s[5]) + (xsq_s[6] + xsq_s[7]));
        cur_xs = fmaxf(sqrtf(ssX), 1e-6f);
        float xn = cur_be0 / cur_xs;
        x_s[tid + (tid >> 6) * 4] = fminf(fmaxf(xn, -1.f), 1.f);
        __syncthreads();
        const float* xb = x_s + kc * 68;
        float q0 = 0.f, q1 = 0.f, q2 = 0.f, q3 = 0.f;
        #pragma unroll
        for (int i = 0; i < 16; ++i) {
            float4 v4 = *(const float4*)(xb + 4 * i);
            q0 += wB[i].x * v4.x; q1 += wB[i].y * v4.y;
            q2 += wB[i].z * v4.z; q3 += wB[i].w * v4.w;
        }
        float bq = (q0 + q1) + (q2 + q3);
        bq += __shfl_down(bq, 4, 8);
        bq += __shfl_down(bq, 2, 8);
        bq += __shfl_down(bq, 1, 8);
        if (lead) {
            cur_be1 = bq;
            __builtin_nontemporal_store(bq, &be1g[(size_t)chain * HID + j2]);
        }
        __syncthreads();   // x_s free; h_s visible
    }

    for (int t = 0; t < T_LEN; ++t) {
        // issue next-row stream early (consumed in the slack window)
        float nxt_be0 = 0.f;
        if (t + 1 < T_LEN)
            nxt_be0 = be0g[(size_t)((t + 1) * BATCH + chain) * HID + tid];
        const unsigned tag = (unsigned)(t + 1);
        unsigned long long* ps = pc + (size_t)(t & 1) * (SL * HID);

        // ---- phase 1: 64-MAC partial of dp[tid] over own h slice ----
        {
            float p0 = 0.f, p1 = 0.f, p2 = 0.f, p3 = 0.f;
            #pragma unroll
            for (int i = 0; i < 16; ++i) {
                float4 hv = *(const float4*)(h_s + 4 * i);   // broadcast, no conflict
                p0 += wC[i].x * hv.x; p1 += wC[i].y * hv.y;
                p2 += wC[i].z * hv.z; p3 += wC[i].w * hv.w;
            }
            float pp = (p0 + p1) + (p2 + p3);
            __hip_atomic_store(&ps[slice * HID + tid], pack_pair(pp, tag),
                               __ATOMIC_RELAXED, __HIP_MEMORY_SCOPE_AGENT);
        }

        // ---- slack window (partials in flight): be1(t+1) + xs(t+1), local ----
        float nxt_xs = 0.f, nxt_be1 = 0.f;
        if (t + 1 < T_LEN) {
            float sq = nxt_be0 * nxt_be0;
            #pragma unroll
            for (int off = 32; off > 0; off >>= 1) sq += __shfl_down(sq, off, 64);
            if (lane == 0) xsq_s[w] = sq;
            __syncthreads();
            float ssX = ((xsq_s[0] + xsq_s[1]) + (xsq_s[2] + xsq_s[3]))
                      + ((xsq_s[4] + xsq_s[5]) + (xsq_s[6] + xsq_s[7]));
            nxt_xs = fmaxf(sqrtf(ssX), 1e-6f);
            float xn = nxt_be0 / nxt_xs;
            x_s[tid + (tid >> 6) * 4] = fminf(fmaxf(xn, -1.f), 1.f);
            __syncthreads();
            const float* xb = x_s + kc * 68;
            float q0 = 0.f, q1 = 0.f, q2 = 0.f, q3 = 0.f;
            #pragma unroll
            for (int i = 0; i < 16; ++i) {
                float4 v4 = *(const float4*)(xb + 4 * i);
                q0 += wB[i].x * v4.x; q1 += wB[i].y * v4.y;
                q2 += wB[i].z * v4.z; q3 += wB[i].w * v4.w;
            }
            float bq = (q0 + q1) + (q2 + q3);
            bq += __shfl_down(bq, 4, 8);
            bq += __shfl_down(bq, 2, 8);
            bq += __shfl_down(bq, 1, 8);
            if (lead) {
                nxt_be1 = bq;
                __builtin_nontemporal_store(bq,
                    &be1g[(size_t)((t + 1) * BATCH + chain) * HID + j2]);
            }
        }

        // ---- poll: 8 single-producer pairs, ONE asm round-trip per round ----
        float dp;
        {
            const unsigned long long* a0 = ps + 0 * HID + tid;
            const unsigned long long* a1p = ps + 1 * HID + tid;
            const unsigned long long* a2 = ps + 2 * HID + tid;
            const unsigned long long* a3 = ps + 3 * HID + tid;
            const unsigned long long* a4 = ps + 4 * HID + tid;
            const unsigned long long* a5 = ps + 5 * HID + tid;
            const unsigned long long* a6 = ps + 6 * HID + tid;
            const unsigned long long* a7 = ps + 7 * HID + tid;
            unsigned long long q0, q1, q2, q3, q4, q5, q6, q7;
            int rounds = 0;
            for (;;) {
                asm volatile(
                    "global_load_dwordx2 %0, %8, off sc0 sc1\n\t"
                    "global_load_dwordx2 %1, %9, off sc0 sc1\n\t"
                    "global_load_dwordx2 %2, %10, off sc0 sc1\n\t"
                    "global_load_dwordx2 %3, %11, off sc0 sc1\n\t"
                    "global_load_dwordx2 %4, %12, off sc0 sc1\n\t"
                    "global_load_dwordx2 %5, %13, off sc0 sc1\n\t"
                    "global_load_dwordx2 %6, %14, off sc0 sc1\n\t"
                    "global_load_dwordx2 %7, %15, off sc0 sc1\n\t"
                    "s_waitcnt vmcnt(0)"
                    : "=&v"(q0), "=&v"(q1), "=&v"(q2), "=&v"(q3),
                      "=&v"(q4), "=&v"(q5), "=&v"(q6), "=&v"(q7)
                    : "v"(a0), "v"(a1p), "v"(a2), "v"(a3),
                      "v"(a4), "v"(a5), "v"(a6), "v"(a7)
                    : "memory");
                bool ok = (pair_epoch(q0) == tag) & (pair_epoch(q1) == tag)
                        & (pair_epoch(q2) == tag) & (pair_epoch(q3) == tag)
                        & (pair_epoch(q4) == tag) & (pair_epoch(q5) == tag)
                        & (pair_epoch(q6) == tag) & (pair_epoch(q7) == tag);
                if (__all(ok)) break;
                // guaranteed-progress fallback: proven atomic gather
                if (++rounds > 200000) {
                    q0 = __hip_atomic_load(a0, __ATOMIC_RELAXED, __HIP_MEMORY_SCOPE_AGENT);
                    q1 = __hip_atomic_load(a1p, __ATOMIC_RELAXED, __HIP_MEMORY_SCOPE_AGENT);
                    q2 = __hip_atomic_load(a2, __ATOMIC_RELAXED, __HIP_MEMORY_SCOPE_AGENT);
                    q3 = __hip_atomic_load(a3, __ATOMIC_RELAXED, __HIP_MEMORY_SCOPE_AGENT);
                    q4 = __hip_atomic_load(a4, __ATOMIC_RELAXED, __HIP_MEMORY_SCOPE_AGENT);
                    q5 = __hip_atomic_load(a5, __ATOMIC_RELAXED, __HIP_MEMORY_SCOPE_AGENT);
                    q6 = __hip_atomic_load(a6, __ATOMIC_RELAXED, __HIP_MEMORY_SCOPE_AGENT);
                    q7 = __hip_atomic_load(a7, __ATOMIC_RELAXED, __HIP_MEMORY_SCOPE_AGENT);
                    bool ok2 = (pair_epoch(q0) == tag) & (pair_epoch(q1) == tag)
                             & (pair_epoch(q2) == tag) & (pair_epoch(q3) == tag)
                             & (pair_epoch(q4) == tag) & (pair_epoch(q5) == tag)
                             & (pair_epoch(q6) == tag) & (pair_epoch(q7) == tag);
                    if (__all(ok2)) break;
                    rounds = 0;
                }
                __builtin_amdgcn_s_sleep(1);
            }
            dp = ((pair_val(q0) + pair_val(q1)) + (pair_val(q2) + pair_val(q3)))
               + ((pair_val(q4) + pair_val(q5)) + (pair_val(q6) + pair_val(q7)));
        }

        // ---- err vector; stage padded for conflict-free phase 2 ----
        {
            float err = cur_be0 - fast_tanh(dp) * cur_xs;
            e_s[tid + (tid >> 6) * 4] = err;
            float sq = err * err;
            #pragma unroll
            for (int off = 32; off > 0; off >>= 1) sq += __shfl_down(sq, off, 64);
            if (lane == 0) sq_s[w] = sq;
        }
        __syncthreads();   // e_s + sq_s complete

        // ---- phase 2: ee = (err @ W1^T)[j2] over k-chunk, gated update ----
        {
            float ssT = ((sq_s[0] + sq_s[1]) + (sq_s[2] + sq_s[3]))
                      + ((sq_s[4] + sq_s[5]) + (sq_s[6] + sq_s[7]));
            const float* esb = e_s + kc * 68;
            float q0 = 0.f, q1 = 0.f, q2 = 0.f, q3 = 0.f;
            #pragma unroll
            for (int i = 0; i < 16; ++i) {
                float4 ev = *(const float4*)(esb + 4 * i);   // 8 groups x 16B = 32 banks
                q0 += wW[i].x * ev.x; q1 += wW[i].y * ev.y;
                q2 += wW[i].z * ev.z; q3 += wW[i].w * ev.w;
            }
            float ee = (q0 + q1) + (q2 + q3);
            ee += __shfl_down(ee, 4, 8);
            ee += __shfl_down(ee, 2, 8);
            ee += __shfl_down(ee, 1, 8);
            if (lead) {
                float rel = fminf(sqrtf(ssT) / cur_xs, 4.0f);
                float s = fast_sigmoid((rel - tauv) / gamv);
                float input_h = hj * 0.2f + cur_be1 * 0.6f + ee * s * 0.2f;
                float g = s * siga;
                hj = hj * (1.f - g) + fast_tanh(input_h) * g;
                h_s[jq] = hj;
                __builtin_nontemporal_store(hj,
                    &h1s[(size_t)(t * BATCH + chain) * HID + j2]);
            }
        }
        __syncthreads();   // h_s ready for next step; e_s/x_s reads done

        cur_be0 = nxt_be0; cur_be1 = nxt_be1; cur_xs = nxt_xs;
    }
}

// K4: head matmul out[b,t,c] = [h1 || be1] @ head_w^T + head_b
__global__ __launch_bounds__(1024) void k4_head(const float* __restrict__ h1s,
                                                const float* __restrict__ be1,
                                                const float* __restrict__ head_w,
                                                const float* __restrict__ head_b,
                                                float* __restrict__ out) {
    const int t = blockIdx.x;
    const int tid = threadIdx.x;
    const int c = tid >> 4;
    const int b = tid & 15;
    const float* hw = head_w + c * (2 * HID);
    const float* x1 = h1s + (size_t)(t * BATCH + b) * HID;
    const float* x2 = be1 + (size_t)(t * BATCH + b) * HID;
    float acc0 = head_b[c], acc1 = 0.f;
    for (int k = 0; k < HID; k += 4) {
        float4 w = *(const float4*)(hw + k);
        float4 xv = *(const float4*)(x1 + k);
        acc0 += w.x * xv.x + w.y * xv.y + w.z * xv.z + w.w * xv.w;
    }
    for (int k = 0; k < HID; k += 4) {
        float4 w = *(const float4*)(hw + HID + k);
        float4 xv = *(const float4*)(x2 + k);
        acc1 += w.x * xv.x + w.y * xv.y + w.z * xv.z + w.w * xv.w;
    }
    out[b * (T_LEN * NCLS) + t * NCLS + c] = acc0 + acc1;
}

extern "C" void kernel_launch(void* const* d_in, const int* in_sizes, int n_in,
                              void* d_out, int out_size, void* d_ws, size_t ws_size,
                              hipStream_t stream) {
    const float* feats  = (const float*)d_in[0];
    const float* B0     = (const float*)d_in[2];
    const float* C1     = (const float*)d_in[7];
    const float* B1     = (const float*)d_in[8];
    const float* W1     = (const float*)d_in[9];
    const float* a1     = (const float*)d_in[10];
    const float* tau1   = (const float*)d_in[11];
    const float* gam1   = (const float*)d_in[12];
    const float* head_w = (const float*)d_in[13];
    const float* head_b = (const float*)d_in[14];
    float* out = (float*)d_out;

    float* be0 = (float*)d_ws;                          // T*B*HID
    float* be1 = be0 + (size_t)T_LEN * BATCH * HID;     // T*B*HID (k3-written)
    float* h1s = be1 + (size_t)T_LEN * BATCH * HID;     // T*B*HID
    unsigned long long* part =
        (unsigned long long*)(h1s + (size_t)T_LEN * BATCH * HID);  // PART_WORDS u64

    hipLaunchKernelGGL(k0_init, dim3(512), dim3(256), 0, stream, part);
    hipLaunchKernelGGL(k1_be0, dim3(T_LEN), dim3(256), 0, stream, feats, B0, be0);
    hipLaunchKernelGGL(k3_fused, dim3(BATCH * SL), dim3(512), 0, stream,
                       be0, C1, W1, B1, a1, tau1, gam1, be1, h1s, part);
    hipLaunchKernelGGL(k4_head, dim3(T_LEN), dim3(1024), 0, stream,
                       h1s, be1, head_w, head_b, out);
}

// Round 15
// 3483.972 us; speedup vs baseline: 1.4094x; 1.1282x over previous
//
#include <hip/hip_runtime.h>
#include <math.h>

#define T_LEN 1000
#define BATCH 16
#define MEL   80
#define HID   512
#define NCLS  64
#define SL    8        // blocks per chain (8 x 512 threads) — register-feasible geometry

__device__ __forceinline__ float fast_tanh(float x) {
    float e = __expf(2.0f * x);
    return 1.0f - 2.0f / (e + 1.0f);
}
__device__ __forceinline__ float fast_sigmoid(float x) {
    return 1.0f / (1.0f + __expf(-x));
}

// packed (value, epoch) 8B atom. Published via __hip_atomic_store AGENT,
// polled via the r6-proven one-wait asm gather (fused data+validity in ONE
// load stage). Exchange ledger CLOSED: serialized loads (r4) n.s., one-wait
// (r6) n.s., flags (r3) / interleaved lines (r5) / tails (r8) all WORSE
// => ~3.3us/step is the rendezvous floor. Slack-fusion ledger: be1 GEMM in
// the publish->poll window = WIN (r9); head partial in the window = LOSS at
// all three placements (r10/r12/r13) — do not re-add.
__device__ __forceinline__ unsigned long long pack_pair(float v, unsigned e) {
    return ((unsigned long long)e << 32) | (unsigned long long)__float_as_uint(v);
}
__device__ __forceinline__ float pair_val(unsigned long long p) {
    return __uint_as_float((unsigned)(p & 0xffffffffull));
}
__device__ __forceinline__ unsigned pair_epoch(unsigned long long p) {
    return (unsigned)(p >> 32);
}

// one-shot LLC bulk load of 64 CONTIGUOUS floats (asm-defined => cannot be
// rematerialized => register-resident). NOT used in any spin loop.
__device__ __forceinline__ void llc_load16c(const float* base, float4 (&r)[16]) {
    asm volatile(
        "global_load_dwordx4 %0, %16, off sc0 sc1\n\t"
        "global_load_dwordx4 %1, %16, off offset:16 sc0 sc1\n\t"
        "global_load_dwordx4 %2, %16, off offset:32 sc0 sc1\n\t"
        "global_load_dwordx4 %3, %16, off offset:48 sc0 sc1\n\t"
        "global_load_dwordx4 %4, %16, off offset:64 sc0 sc1\n\t"
        "global_load_dwordx4 %5, %16, off offset:80 sc0 sc1\n\t"
        "global_load_dwordx4 %6, %16, off offset:96 sc0 sc1\n\t"
        "global_load_dwordx4 %7, %16, off offset:112 sc0 sc1\n\t"
        "global_load_dwordx4 %8, %16, off offset:128 sc0 sc1\n\t"
        "global_load_dwordx4 %9, %16, off offset:144 sc0 sc1\n\t"
        "global_load_dwordx4 %10, %16, off offset:160 sc0 sc1\n\t"
        "global_load_dwordx4 %11, %16, off offset:176 sc0 sc1\n\t"
        "global_load_dwordx4 %12, %16, off offset:192 sc0 sc1\n\t"
        "global_load_dwordx4 %13, %16, off offset:208 sc0 sc1\n\t"
        "global_load_dwordx4 %14, %16, off offset:224 sc0 sc1\n\t"
        "global_load_dwordx4 %15, %16, off offset:240 sc0 sc1\n\t"
        "s_waitcnt vmcnt(0)"
        : "=&v"(r[0]), "=&v"(r[1]), "=&v"(r[2]), "=&v"(r[3]),
          "=&v"(r[4]), "=&v"(r[5]), "=&v"(r[6]), "=&v"(r[7]),
          "=&v"(r[8]), "=&v"(r[9]), "=&v"(r[10]), "=&v"(r[11]),
          "=&v"(r[12]), "=&v"(r[13]), "=&v"(r[14]), "=&v"(r[15])
        : "v"(base)
        : "memory");
}

// K0: init pair buffer to epoch 0 (never matches poll targets >= 1).
#define PART_WORDS (BATCH * 2 * SL * HID)
__global__ void k0_init(unsigned long long* part) {
    int i = blockIdx.x * 256 + threadIdx.x;
    if (i < PART_WORDS) part[i] = 0ull;
}

// K1: per t: x_norm0 from feats, be0 = x_norm0 @ B0^T
__global__ __launch_bounds__(256) void k1_be0(const float* __restrict__ feats,
                                              const float* __restrict__ B0,
                                              float* __restrict__ be0) {
    const int t = blockIdx.x;
    const int tid = threadIdx.x;
    __shared__ float xf[BATCH][MEL];
    __shared__ float sc[BATCH];
    for (int idx = tid; idx < BATCH * MEL; idx += 256) {
        int b = idx / MEL, m = idx % MEL;
        xf[b][m] = feats[b * (T_LEN * MEL) + t * MEL + m];
    }
    __syncthreads();
    if (tid < BATCH) {
        float ss = 0.f;
        for (int m = 0; m < MEL; ++m) { float v = xf[tid][m]; ss += v * v; }
        sc[tid] = fmaxf(sqrtf(ss), 1e-6f);
    }
    __syncthreads();
    for (int idx = tid; idx < BATCH * MEL; idx += 256) {
        int b = idx / MEL, m = idx % MEL;
        float v = xf[b][m] / sc[b];
        xf[b][m] = fminf(fmaxf(v, -1.f), 1.f);
    }
    __syncthreads();
    for (int j = tid; j < HID; j += 256) {
        float acc[BATCH];
        #pragma unroll
        for (int b = 0; b < BATCH; ++b) acc[b] = 0.f;
        const float* brow = B0 + j * MEL;
        for (int k = 0; k < MEL; k += 4) {
            float4 w = *(const float4*)(brow + k);
            #pragma unroll
            for (int b = 0; b < BATCH; ++b) {
                float4 xv = *(const float4*)(&xf[b][k]);
                acc[b] += w.x * xv.x + w.y * xv.y + w.z * xv.z + w.w * xv.w;
            }
        }
        #pragma unroll
        for (int b = 0; b < BATCH; ++b)
            be0[(t * BATCH + b) * HID + j] = acc[b];
    }
}

// K3: sequential recurrence, ONE exchange per step (r6-proven exchange) with
// be1/xs FUSED into the publish->poll slack window (k2 deleted). BYTE-
// IDENTICAL to the r9/r14-proven kernel (3340us).
__global__ __launch_bounds__(512, 1) void k3_fused(
    const float* __restrict__ be0g,
    const float* __restrict__ C1, const float* __restrict__ W1,
    const float* __restrict__ B1,
    const float* __restrict__ a1, const float* __restrict__ tau,
    const float* __restrict__ gam,
    float* __restrict__ be1g, float* __restrict__ h1s,
    unsigned long long* part)
{
    const int chain = blockIdx.x & 15;
    const int slice = blockIdx.x >> 4;        // 0..7
    const int tid = threadIdx.x;              // 0..511 ; phase-1 row = tid
    const int w = tid >> 6;                   // wave 0..7
    const int lane = tid & 63;
    const int jq = tid >> 3;                  // phase-2 column within slice 0..63
    const int kc = tid & 7;                   // phase-2 k-chunk 0..7
    const int j2 = slice * 64 + jq;           // phase-2 global output column
    const bool lead = (kc == 0);

    float4 wC[16], wW[16], wB[16];
    llc_load16c(C1 + (size_t)tid * HID + slice * 64, wC);
    llc_load16c(W1 + (size_t)j2 * HID + kc * 64, wW);
    llc_load16c(B1 + (size_t)j2 * HID + kc * 64, wB);

    const float tauv = tau[0], gamv = gam[0];
    const float siga = fast_sigmoid(a1[j2]);

    unsigned long long* pc = part + (size_t)chain * (2 * SL * HID);

    __shared__ float h_s[64];                      // own h slice (broadcast reads)
    __shared__ __align__(16) float e_s[HID + 32];  // err, padded per 64-chunk
    __shared__ __align__(16) float x_s[HID + 32];  // normalized be0 row, padded
    __shared__ float sq_s[8];
    __shared__ float xsq_s[8];

    float hj = 0.f;                           // lead lanes: h for column j2
    if (tid < 64) h_s[tid] = 0.f;

    // ---- prologue: t=0 streams; compute cur_xs, cur_be1 locally ----
    float cur_be0 = be0g[(size_t)chain * HID + tid];
    float cur_xs, cur_be1 = 0.f;
    {
        float sq = cur_be0 * cur_be0;
        #pragma unroll
        for (int off = 32; off > 0; off >>= 1) sq += __shfl_down(sq, off, 64);
        if (lane == 0) xsq_s[w] = sq;
        __syncthreads();
        float ssX = ((xsq_s[0] + xsq_s[1]) + (xsq_s[2] + xsq_s[3]))
                  + ((xsq_s[4] + xsq_s[5]) + (xsq_s[6] + xsq_s[7]));
        cur_xs = fmaxf(sqrtf(ssX), 1e-6f);
        float xn = cur_be0 / cur_xs;
        x_s[tid + (tid >> 6) * 4] = fminf(fmaxf(xn, -1.f), 1.f);
        __syncthreads();
        const float* xb = x_s + kc * 68;
        float q0 = 0.f, q1 = 0.f, q2 = 0.f, q3 = 0.f;
        #pragma unroll
        for (int i = 0; i < 16; ++i) {
            float4 v4 = *(const float4*)(xb + 4 * i);
            q0 += wB[i].x * v4.x; q1 += wB[i].y * v4.y;
            q2 += wB[i].z * v4.z; q3 += wB[i].w * v4.w;
        }
        float bq = (q0 + q1) + (q2 + q3);
        bq += __shfl_down(bq, 4, 8);
        bq += __shfl_down(bq, 2, 8);
        bq += __shfl_down(bq, 1, 8);
        if (lead) {
            cur_be1 = bq;
            __builtin_nontemporal_store(bq, &be1g[(size_t)chain * HID + j2]);
        }
        __syncthreads();   // x_s free; h_s visible
    }

    for (int t = 0; t < T_LEN; ++t) {
        // issue next-row stream early (consumed in the slack window)
        float nxt_be0 = 0.f;
        if (t + 1 < T_LEN)
            nxt_be0 = be0g[(size_t)((t + 1) * BATCH + chain) * HID + tid];
        const unsigned tag = (unsigned)(t + 1);
        unsigned long long* ps = pc + (size_t)(t & 1) * (SL * HID);

        // ---- phase 1: 64-MAC partial of dp[tid] over own h slice ----
        {
            float p0 = 0.f, p1 = 0.f, p2 = 0.f, p3 = 0.f;
            #pragma unroll
            for (int i = 0; i < 16; ++i) {
                float4 hv = *(const float4*)(h_s + 4 * i);   // broadcast, no conflict
                p0 += wC[i].x * hv.x; p1 += wC[i].y * hv.y;
                p2 += wC[i].z * hv.z; p3 += wC[i].w * hv.w;
            }
            float pp = (p0 + p1) + (p2 + p3);
            __hip_atomic_store(&ps[slice * HID + tid], pack_pair(pp, tag),
                               __ATOMIC_RELAXED, __HIP_MEMORY_SCOPE_AGENT);
        }

        // ---- slack window (partials in flight): be1(t+1) + xs(t+1), local ----
        float nxt_xs = 0.f, nxt_be1 = 0.f;
        if (t + 1 < T_LEN) {
            float sq = nxt_be0 * nxt_be0;
            #pragma unroll
            for (int off = 32; off > 0; off >>= 1) sq += __shfl_down(sq, off, 64);
            if (lane == 0) xsq_s[w] = sq;
            __syncthreads();
            float ssX = ((xsq_s[0] + xsq_s[1]) + (xsq_s[2] + xsq_s[3]))
                      + ((xsq_s[4] + xsq_s[5]) + (xsq_s[6] + xsq_s[7]));
            nxt_xs = fmaxf(sqrtf(ssX), 1e-6f);
            float xn = nxt_be0 / nxt_xs;
            x_s[tid + (tid >> 6) * 4] = fminf(fmaxf(xn, -1.f), 1.f);
            __syncthreads();
            const float* xb = x_s + kc * 68;
            float q0 = 0.f, q1 = 0.f, q2 = 0.f, q3 = 0.f;
            #pragma unroll
            for (int i = 0; i < 16; ++i) {
                float4 v4 = *(const float4*)(xb + 4 * i);
                q0 += wB[i].x * v4.x; q1 += wB[i].y * v4.y;
                q2 += wB[i].z * v4.z; q3 += wB[i].w * v4.w;
            }
            float bq = (q0 + q1) + (q2 + q3);
            bq += __shfl_down(bq, 4, 8);
            bq += __shfl_down(bq, 2, 8);
            bq += __shfl_down(bq, 1, 8);
            if (lead) {
                nxt_be1 = bq;
                __builtin_nontemporal_store(bq,
                    &be1g[(size_t)((t + 1) * BATCH + chain) * HID + j2]);
            }
        }

        // ---- poll: 8 single-producer pairs, ONE asm round-trip per round ----
        float dp;
        {
            const unsigned long long* a0 = ps + 0 * HID + tid;
            const unsigned long long* a1p = ps + 1 * HID + tid;
            const unsigned long long* a2 = ps + 2 * HID + tid;
            const unsigned long long* a3 = ps + 3 * HID + tid;
            const unsigned long long* a4 = ps + 4 * HID + tid;
            const unsigned long long* a5 = ps + 5 * HID + tid;
            const unsigned long long* a6 = ps + 6 * HID + tid;
            const unsigned long long* a7 = ps + 7 * HID + tid;
            unsigned long long q0, q1, q2, q3, q4, q5, q6, q7;
            int rounds = 0;
            for (;;) {
                asm volatile(
                    "global_load_dwordx2 %0, %8, off sc0 sc1\n\t"
                    "global_load_dwordx2 %1, %9, off sc0 sc1\n\t"
                    "global_load_dwordx2 %2, %10, off sc0 sc1\n\t"
                    "global_load_dwordx2 %3, %11, off sc0 sc1\n\t"
                    "global_load_dwordx2 %4, %12, off sc0 sc1\n\t"
                    "global_load_dwordx2 %5, %13, off sc0 sc1\n\t"
                    "global_load_dwordx2 %6, %14, off sc0 sc1\n\t"
                    "global_load_dwordx2 %7, %15, off sc0 sc1\n\t"
                    "s_waitcnt vmcnt(0)"
                    : "=&v"(q0), "=&v"(q1), "=&v"(q2), "=&v"(q3),
                      "=&v"(q4), "=&v"(q5), "=&v"(q6), "=&v"(q7)
                    : "v"(a0), "v"(a1p), "v"(a2), "v"(a3),
                      "v"(a4), "v"(a5), "v"(a6), "v"(a7)
                    : "memory");
                bool ok = (pair_epoch(q0) == tag) & (pair_epoch(q1) == tag)
                        & (pair_epoch(q2) == tag) & (pair_epoch(q3) == tag)
                        & (pair_epoch(q4) == tag) & (pair_epoch(q5) == tag)
                        & (pair_epoch(q6) == tag) & (pair_epoch(q7) == tag);
                if (__all(ok)) break;
                // guaranteed-progress fallback: proven atomic gather
                if (++rounds > 200000) {
                    q0 = __hip_atomic_load(a0, __ATOMIC_RELAXED, __HIP_MEMORY_SCOPE_AGENT);
                    q1 = __hip_atomic_load(a1p, __ATOMIC_RELAXED, __HIP_MEMORY_SCOPE_AGENT);
                    q2 = __hip_atomic_load(a2, __ATOMIC_RELAXED, __HIP_MEMORY_SCOPE_AGENT);
                    q3 = __hip_atomic_load(a3, __ATOMIC_RELAXED, __HIP_MEMORY_SCOPE_AGENT);
                    q4 = __hip_atomic_load(a4, __ATOMIC_RELAXED, __HIP_MEMORY_SCOPE_AGENT);
                    q5 = __hip_atomic_load(a5, __ATOMIC_RELAXED, __HIP_MEMORY_SCOPE_AGENT);
                    q6 = __hip_atomic_load(a6, __ATOMIC_RELAXED, __HIP_MEMORY_SCOPE_AGENT);
                    q7 = __hip_atomic_load(a7, __ATOMIC_RELAXED, __HIP_MEMORY_SCOPE_AGENT);
                    bool ok2 = (pair_epoch(q0) == tag) & (pair_epoch(q1) == tag)
                             & (pair_epoch(q2) == tag) & (pair_epoch(q3) == tag)
                             & (pair_epoch(q4) == tag) & (pair_epoch(q5) == tag)
                             & (pair_epoch(q6) == tag) & (pair_epoch(q7) == tag);
                    if (__all(ok2)) break;
                    rounds = 0;
                }
                __builtin_amdgcn_s_sleep(1);
            }
            dp = ((pair_val(q0) + pair_val(q1)) + (pair_val(q2) + pair_val(q3)))
               + ((pair_val(q4) + pair_val(q5)) + (pair_val(q6) + pair_val(q7)));
        }

        // ---- err vector; stage padded for conflict-free phase 2 ----
        {
            float err = cur_be0 - fast_tanh(dp) * cur_xs;
            e_s[tid + (tid >> 6) * 4] = err;
            float sq = err * err;
            #pragma unroll
            for (int off = 32; off > 0; off >>= 1) sq += __shfl_down(sq, off, 64);
            if (lane == 0) sq_s[w] = sq;
        }
        __syncthreads();   // e_s + sq_s complete

        // ---- phase 2: ee = (err @ W1^T)[j2] over k-chunk, gated update ----
        {
            float ssT = ((sq_s[0] + sq_s[1]) + (sq_s[2] + sq_s[3]))
                      + ((sq_s[4] + sq_s[5]) + (sq_s[6] + sq_s[7]));
            const float* esb = e_s + kc * 68;
            float q0 = 0.f, q1 = 0.f, q2 = 0.f, q3 = 0.f;
            #pragma unroll
            for (int i = 0; i < 16; ++i) {
                float4 ev = *(const float4*)(esb + 4 * i);   // 8 groups x 16B = 32 banks
                q0 += wW[i].x * ev.x; q1 += wW[i].y * ev.y;
                q2 += wW[i].z * ev.z; q3 += wW[i].w * ev.w;
            }
            float ee = (q0 + q1) + (q2 + q3);
            ee += __shfl_down(ee, 4, 8);
            ee += __shfl_down(ee, 2, 8);
            ee += __shfl_down(ee, 1, 8);
            if (lead) {
                float rel = fminf(sqrtf(ssT) / cur_xs, 4.0f);
                float s = fast_sigmoid((rel - tauv) / gamv);
                float input_h = hj * 0.2f + cur_be1 * 0.6f + ee * s * 0.2f;
                float g = s * siga;
                hj = hj * (1.f - g) + fast_tanh(input_h) * g;
                h_s[jq] = hj;
                __builtin_nontemporal_store(hj,
                    &h1s[(size_t)(t * BATCH + chain) * HID + j2]);
            }
        }
        __syncthreads();   // h_s ready for next step; e_s/x_s reads done

        cur_be0 = nxt_be0; cur_be1 = nxt_be1; cur_xs = nxt_xs;
    }
}

// K4 v2: out[b,t,c] = [h1 || be1] @ head_w^T + head_b, k3-style.
//   512 threads = (c = tid>>3, kc = tid&7). head_w[c][kc*128..+128) register-
//   resident (32 f4 via llc_load16c). x = [h1s[t] || be1[t]] (16x1024 floats)
//   staged COALESCED into chunk-padded LDS (idx k + (k>>7)*4: kc-slices at
//   132-float stride -> 8 broadcast groups x 4 banks = all 32 banks,
//   conflict-free). 16 b-iterations x 32 f4 MACs, width-8 shfl reduce,
//   kc==0 adds bias and stores. Replaces the per-thread strided-row k4
//   (each thread privately streamed 4KB uncoalesced -> ~250us for a 13us
//   FLOP + 65MB kernel).
__global__ __launch_bounds__(512) void k4_head(const float* __restrict__ h1s,
                                               const float* __restrict__ be1,
                                               const float* __restrict__ head_w,
                                               const float* __restrict__ head_b,
                                               float* __restrict__ out) {
    const int t = blockIdx.x;
    const int tid = threadIdx.x;
    const int c = tid >> 3;                   // class 0..63
    const int kc = tid & 7;                   // k-chunk 0..7 (128 floats each)

    float4 wA[16], wB4[16];
    llc_load16c(head_w + (size_t)c * (2 * HID) + kc * 128, wA);
    llc_load16c(head_w + (size_t)c * (2 * HID) + kc * 128 + 64, wB4);
    const float hb = head_b[c];

    // padded: row stride 1056 floats; idx = k + (k>>7)*4 within a row
    __shared__ __align__(16) float xs[BATCH * 1056];

    // coalesced stage: 4096 float4 total, 8 per thread
    const float* src1 = h1s + (size_t)t * BATCH * HID;
    const float* src2 = be1 + (size_t)t * BATCH * HID;
    #pragma unroll
    for (int j = 0; j < 8; ++j) {
        int fidx = tid + j * 512;             // 0..4095
        int b = fidx >> 8;                    // 256 f4 per batch row
        int r = fidx & 255;
        int k0 = r * 4;                       // 0..1020
        float4 v = (k0 < HID)
                 ? *(const float4*)(src1 + (size_t)b * HID + k0)
                 : *(const float4*)(src2 + (size_t)b * HID + (k0 - HID));
        *(float4*)(&xs[b * 1056 + k0 + (k0 >> 7) * 4]) = v;
    }
    __syncthreads();

    #pragma unroll
    for (int b = 0; b < BATCH; ++b) {
        const float* xb = xs + b * 1056 + kc * 132;
        float q0 = 0.f, q1 = 0.f, q2 = 0.f, q3 = 0.f;
        #pragma unroll
        for (int i = 0; i < 16; ++i) {
            float4 v4 = *(const float4*)(xb + 4 * i);
            q0 += wA[i].x * v4.x; q1 += wA[i].y * v4.y;
            q2 += wA[i].z * v4.z; q3 += wA[i].w * v4.w;
        }
        #pragma unroll
        for (int i = 0; i < 16; ++i) {
            float4 v4 = *(const float4*)(xb + 64 + 4 * i);
            q0 += wB4[i].x * v4.x; q1 += wB4[i].y * v4.y;
            q2 += wB4[i].z * v4.z; q3 += wB4[i].w * v4.w;
        }
        float p = (q0 + q1) + (q2 + q3);
        p += __shfl_down(p, 4, 8);
        p += __shfl_down(p, 2, 8);
        p += __shfl_down(p, 1, 8);
        if (kc == 0)
            out[b * (T_LEN * NCLS) + t * NCLS + c] = p + hb;
    }
}

extern "C" void kernel_launch(void* const* d_in, const int* in_sizes, int n_in,
                              void* d_out, int out_size, void* d_ws, size_t ws_size,
                              hipStream_t stream) {
    const float* feats  = (const float*)d_in[0];
    const float* B0     = (const float*)d_in[2];
    const float* C1     = (const float*)d_in[7];
    const float* B1     = (const float*)d_in[8];
    const float* W1     = (const float*)d_in[9];
    const float* a1     = (const float*)d_in[10];
    const float* tau1   = (const float*)d_in[11];
    const float* gam1   = (const float*)d_in[12];
    const float* head_w = (const float*)d_in[13];
    const float* head_b = (const float*)d_in[14];
    float* out = (float*)d_out;

    float* be0 = (float*)d_ws;                          // T*B*HID
    float* be1 = be0 + (size_t)T_LEN * BATCH * HID;     // T*B*HID (k3-written)
    float* h1s = be1 + (size_t)T_LEN * BATCH * HID;     // T*B*HID
    unsigned long long* part =
        (unsigned long long*)(h1s + (size_t)T_LEN * BATCH * HID);  // PART_WORDS u64

    hipLaunchKernelGGL(k0_init, dim3(512), dim3(256), 0, stream, part);
    hipLaunchKernelGGL(k1_be0, dim3(T_LEN), dim3(256), 0, stream, feats, B0, be0);
    hipLaunchKernelGGL(k3_fused, dim3(BATCH * SL), dim3(512), 0, stream,
                       be0, C1, W1, B1, a1, tau1, gam1, be1, h1s, part);
    hipLaunchKernelGGL(k4_head, dim3(T_LEN), dim3(512), 0, stream,
                       h1s, be1, head_w, head_b, out);
}